// Round 3
// baseline (47.610 us; speedup 1.0000x reference)
//
#include <hip/hip_runtime.h>
#include <hip/hip_bf16.h>

typedef __attribute__((ext_vector_type(8))) short s16x8;
typedef __attribute__((ext_vector_type(4))) float f32x4;
typedef __attribute__((ext_vector_type(4))) unsigned short u16x4;
typedef __attribute__((ext_vector_type(4))) float fl4;

__device__ __forceinline__ unsigned short f2bf(float f) {
  union { __hip_bfloat16 b; unsigned short u; } cv;
  cv.b = __float2bfloat16(f);
  return cv.u;
}

// ---------------- prepass: fp32 -> bf16 tile images in ws (K and V only) ----
// K image (role 0): per (bh,tile): 64 rows x 64 bf16, LINEAR (no swizzle; no LDS
//   in main kernel so bank conflicts are moot). short idx = y*64 + d.
// V image (role 1): PV-permuted: short idx (((kp*4+g)*64+c)*8 + 4*tu + j)
//   = V[32kp+16tu+4g+j][c] * (1/2048).
__global__ __launch_bounds__(256)
void prep_kv(const float* __restrict__ tk, const float* __restrict__ tv,
             unsigned short* __restrict__ ws)
{
  const int bid  = (int)blockIdx.x;
  const int role = bid >> 9;           // 0=K, 1=V
  const int blk  = bid & 511;          // bh*16 + t
  const int bh = blk >> 4, t = blk & 15;
  const int b = bh >> 2, h = bh & 3;
  const int tid = (int)threadIdx.x;
  unsigned short* dst = ws + (size_t)role * 2097152 + (size_t)blk * 4096;

  if (role == 0) {
    const int sy = tid >> 2, sq4 = tid & 3;
    const float* src = tk + ((size_t)(b*1024 + t*64 + sy))*256 + h*64;
    char* row = (char*)dst + sy*128;
#pragma unroll
    for (int j2 = 0; j2 < 4; ++j2) {
      fl4 v = *(const fl4*)(src + (sq4 + 4*j2)*4);
      u16x4 p;
      p[0] = f2bf(v[0]); p[1] = f2bf(v[1]);
      p[2] = f2bf(v[2]); p[3] = f2bf(v[3]);
      *(u16x4*)(row + (sq4 + 4*j2)*8) = p;
    }
  } else {
    const int vg = tid >> 6, vc = tid & 63;
    const float* src = tv + ((size_t)(b*1024 + t*64))*256 + h*64 + vc;
#pragma unroll
    for (int kp = 0; kp < 2; ++kp)
#pragma unroll
      for (int tu = 0; tu < 2; ++tu) {
        const int y0 = 32*kp + 16*tu + 4*vg;
        u16x4 p;
#pragma unroll
        for (int j2 = 0; j2 < 4; ++j2)
          p[j2] = f2bf(src[(size_t)(y0 + j2)*256] * 4.8828125e-4f);
        *(u16x4*)&dst[((kp*4 + vg)*64 + vc)*8 + 4*tu] = p;
      }
  }
}

// ---------------- main: 1 wave per 16 q-rows, zero LDS, zero barriers ----
// Frags stream global->VGPR; compiler pipelines loads across kv (no syncs).
__global__ __launch_bounds__(64)
void hstu_main(const unsigned short* __restrict__ Kb, const unsigned short* __restrict__ Vb,
               const float* __restrict__ tq, const int* __restrict__ ncand,
               float* __restrict__ out)
{
  const int bid = (int)blockIdx.x;
  const int bh = bid & 31;                    // same bh -> same XCD (stride 32)
  const int jp = bid >> 5;                    // 0..63
  const int rg = (jp == 0) ? 0 : 64 - jp;     // heavy-first dispatch order
  const int b = bh >> 2, h = bh & 3;
  const int l = (int)threadIdx.x;
  const int rl = l & 15, g = l >> 4;
  const int T = 1024 - ncand[b];
  const int qr = rg << 4;                     // wave's 16 q-rows: [qr, qr+16)
  const int rq = qr + rl;

  // Q frags in-reg from fp32 (alpha=1/8 folded): qf0 = d[8g..8g+7], qf1 = d[32+8g..]
  s16x8 qf0, qf1;
  {
    const float* qs = tq + ((size_t)(b*1024 + rq))*256 + h*64 + g*8;
    fl4 a = *(const fl4*)qs, b2 = *(const fl4*)(qs + 4);
    fl4 c = *(const fl4*)(qs + 32), d2 = *(const fl4*)(qs + 36);
#pragma unroll
    for (int j = 0; j < 4; ++j) {
      qf0[j]   = (short)f2bf(a[j]  * 0.125f);
      qf0[j+4] = (short)f2bf(b2[j] * 0.125f);
      qf1[j]   = (short)f2bf(c[j]  * 0.125f);
      qf1[j+4] = (short)f2bf(d2[j] * 0.125f);
    }
  }

  const char* kt = (const char*)(Kb + (size_t)bh * 16 * 4096);
  const char* vt = (const char*)(Vb + (size_t)bh * 16 * 4096);

  f32x4 zero = {0.f, 0.f, 0.f, 0.f};
  f32x4 oacc[4];
#pragma unroll
  for (int i = 0; i < 4; ++i) oacc[i] = zero;

  const int nkv = (rg == 0) ? 16 : (rg >> 2) + 1;   // causal skip (rg0 has contextual rows)

  for (int t = 0; t < nkv; ++t) {
    const char* kimg = kt + (size_t)t * 8192;
    const char* vimg = vt + (size_t)t * 8192;

    // QK^T swapped: S^T[y][q], A=K frag (rows y), B=Q frag
    f32x4 sacc[4];
#pragma unroll
    for (int i = 0; i < 4; ++i) sacc[i] = zero;
#pragma unroll
    for (int t4 = 0; t4 < 4; ++t4) {
      const char* base = kimg + (t4*16 + rl)*128;
      s16x8 kf0 = *(const s16x8*)(base + g*16);
      s16x8 kf1 = *(const s16x8*)(base + 64 + g*16);
      sacc[t4] = __builtin_amdgcn_mfma_f32_16x16x32_bf16(kf0, qf0, sacc[t4], 0, 0, 0);
      sacc[t4] = __builtin_amdgcn_mfma_f32_16x16x32_bf16(kf1, qf1, sacc[t4], 0, 0, 0);
    }
    // silu + mask + pack P into PV A-frags
    s16x8 pa0, pa1;
#pragma unroll
    for (int t4 = 0; t4 < 4; ++t4) {
#pragma unroll
      for (int r = 0; r < 4; ++r) {
        const int y = t*64 + t4*16 + 4*g + r;
        const float s = sacc[t4][r];
        const float sig = __builtin_amdgcn_rcpf(1.f + __expf(-s));
        const bool valid = (rq < 8) ? (y < T)
                         : ((y <= rq) && ((rq < T) || (y < T) || (y == rq)));
        const float a = valid ? s * sig : 0.f;
        const short bv = (short)f2bf(a);
        if (t4 < 2) pa0[(t4 & 1)*4 + r] = bv;
        else        pa1[(t4 & 1)*4 + r] = bv;
      }
    }
    // PV from permuted V image (B-frags are single 16B loads)
#pragma unroll
    for (int vti = 0; vti < 4; ++vti) {
      const s16x8 vf0 = *(const s16x8*)(vimg + (((0*4 + g)*64 + vti*16 + rl)*8)*2);
      oacc[vti] = __builtin_amdgcn_mfma_f32_16x16x32_bf16(pa0, vf0, oacc[vti], 0, 0, 0);
      const s16x8 vf1 = *(const s16x8*)(vimg + (((1*4 + g)*64 + vti*16 + rl)*8)*2);
      oacc[vti] = __builtin_amdgcn_mfma_f32_16x16x32_bf16(pa1, vf1, oacc[vti], 0, 0, 0);
    }
  }

  // epilogue: O rows qr + 4g+r, cols vti*16+rl
  float* dst = out + ((size_t)(b*1024 + qr))*256 + h*64;
#pragma unroll
  for (int vti = 0; vti < 4; ++vti)
#pragma unroll
    for (int r = 0; r < 4; ++r)
      dst[(size_t)(4*g + r)*256 + vti*16 + rl] = oacc[vti][r];
}

extern "C" void kernel_launch(void* const* d_in, const int* in_sizes, int n_in,
                              void* d_out, int out_size, void* d_ws, size_t ws_size,
                              hipStream_t stream) {
  (void)in_sizes; (void)n_in; (void)out_size; (void)ws_size;
  const float* tq = (const float*)d_in[0];
  const float* tk = (const float*)d_in[1];
  const float* tv = (const float*)d_in[2];
  const int*   nc = (const int*)d_in[4];
  float* out = (float*)d_out;
  unsigned short* ws = (unsigned short*)d_ws;   // needs 8 MB

  hipLaunchKernelGGL(prep_kv, dim3(1024), dim3(256), 0, stream, tk, tv, ws);
  const unsigned short* Kb = ws;
  const unsigned short* Vb = ws + 2097152;
  hipLaunchKernelGGL(hstu_main, dim3(2048), dim3(64), 0, stream, Kb, Vb, tq, nc, out);
}